// Round 1
// baseline (232.124 us; speedup 1.0000x reference)
//
#include <hip/hip_runtime.h>

// Xonv2D: location-dependent 3x3 conv.
//   x:       (B=4, CIN=16, H=128, W=128)  fp32
//   weights: (H, W, COUT=16, CIN=16, 3, 3) fp32   -- 151 MB, the traffic driver
//   bias:    (H, W, COUT) fp32
//   out:     (B, COUT, H, W) fp32
//
// One wave per (h,w) site. lane = g*16 + o : o = output channel, g = group of
// 4 input channels. Each lane streams its 36 contiguous weight floats as 9
// aligned float4 loads (64 lanes exactly tile the site's 2304-float block),
// accumulates 4 batch images in registers (weights read once from HBM,
// reused x4), then shfl-reduces over g. Border sites (wave-uniform) take a
// predicated path.

#define HWD  128
#define CIND 16
#define COUTD 16
#define BATCH 4

__global__ __launch_bounds__(256) void xonv2d_kernel(
    const float* __restrict__ x,
    const float* __restrict__ wts,
    const float* __restrict__ bias,
    float* __restrict__ out)
{
    const int lane = threadIdx.x & 63;
    const int wave = threadIdx.x >> 6;
    const int site = blockIdx.x * 4 + wave;   // 0 .. 16383
    const int h = site >> 7;
    const int w = site & 127;

    const int o = lane & 15;    // output channel
    const int g = lane >> 4;    // channel group: c in [4g, 4g+4)
    const int c0 = g * 4;

    // ---- weight stream: 36 contiguous floats for (h,w,o, c0..c0+3, :, :) ----
    // offset (floats): site*2304 + o*144 + g*36 ; byte offsets are 16B-aligned.
    const float4* wp = (const float4*)(wts + (size_t)site * (COUTD * CIND * 9)
                                           + o * (CIND * 9) + g * 36);
    float4 wv[9];
    #pragma unroll
    for (int i = 0; i < 9; ++i) wv[i] = wp[i];
    const float* wf = (const float*)wv;

    float acc[BATCH] = {0.f, 0.f, 0.f, 0.f};

    const bool interior = (h >= 1) & (h <= HWD - 2) & (w >= 1) & (w <= HWD - 2);

    if (interior) {
        #pragma unroll
        for (int cc = 0; cc < 4; ++cc) {
            const float* xc = x + ((size_t)(c0 + cc) * HWD + (h - 1)) * HWD + (w - 1);
            #pragma unroll
            for (int b = 0; b < BATCH; ++b) {
                const float* xb = xc + (size_t)b * (CIND * HWD * HWD);
                #pragma unroll
                for (int kh = 0; kh < 3; ++kh) {
                    #pragma unroll
                    for (int kw = 0; kw < 3; ++kw) {
                        acc[b] = fmaf(xb[kh * HWD + kw], wf[cc * 9 + kh * 3 + kw], acc[b]);
                    }
                }
            }
        }
    } else {
        #pragma unroll
        for (int cc = 0; cc < 4; ++cc) {
            #pragma unroll
            for (int b = 0; b < BATCH; ++b) {
                const float* xb = x + ((size_t)b * CIND + (c0 + cc)) * (HWD * HWD);
                #pragma unroll
                for (int kh = 0; kh < 3; ++kh) {
                    const int hy = h + kh - 1;
                    #pragma unroll
                    for (int kw = 0; kw < 3; ++kw) {
                        const int wx = w + kw - 1;
                        const bool ok = (hy >= 0) & (hy < HWD) & (wx >= 0) & (wx < HWD);
                        const float xv = ok ? xb[hy * HWD + wx] : 0.f;
                        acc[b] = fmaf(xv, wf[cc * 9 + kh * 3 + kw], acc[b]);
                    }
                }
            }
        }
    }

    // ---- reduce the 4 c-groups (lanes o, o+16, o+32, o+48) ----
    #pragma unroll
    for (int b = 0; b < BATCH; ++b) {
        float v = acc[b];
        v += __shfl_down(v, 32);
        v += __shfl_down(v, 16);
        acc[b] = v;
    }

    if (g == 0) {
        const float bv = bias[(size_t)site * COUTD + o];
        #pragma unroll
        for (int b = 0; b < BATCH; ++b) {
            out[((size_t)b * COUTD + o) * (HWD * HWD) + h * HWD + w] = acc[b] + bv;
        }
    }
}

extern "C" void kernel_launch(void* const* d_in, const int* in_sizes, int n_in,
                              void* d_out, int out_size, void* d_ws, size_t ws_size,
                              hipStream_t stream) {
    const float* x    = (const float*)d_in[0];
    const float* wts  = (const float*)d_in[1];
    const float* bias = (const float*)d_in[2];
    float* out = (float*)d_out;

    // 16384 sites, 4 waves (= 4 sites) per 256-thread block.
    const int blocks = (HWD * HWD) / 4;
    xonv2d_kernel<<<blocks, 256, 0, stream>>>(x, wts, bias, out);
}